// Round 9
// baseline (179.978 us; speedup 1.0000x reference)
//
#include <hip/hip_runtime.h>

#define BATCH 4096
#define T 256
#define IN 64
#define CELL 128
#define ZDIM 256
#define OUTD 64
#define M 16   // batch rows per block (one MFMA row-tile)

using f32x4 = __attribute__((ext_vector_type(4))) float;
using f4    = __attribute__((ext_vector_type(4))) float;
using h16x8 = __attribute__((ext_vector_type(8))) _Float16;
using fp16x2 = __attribute__((ext_vector_type(2))) __fp16;   // cvt_pkrtz result type
typedef unsigned int u32t;

union h8cast { h16x8 v; fp16x2 h[4]; };
union pkcast { fp16x2 h; u32t u; };

// gate for cell pair (colA=32w+2q, colB=colA+1) at row 4g+I.
// Weights/biases pre-scaled: f-cols by -log2e, g-cols by 2*log2e, so
// sigmoid(zf) = rcp(1+exp2(zf')) and tanh(zg) = 1-2*rcp(exp2(zg')+1).
#define GATEPK(I)                                                               \
  {                                                                             \
    float zfA = fa0[I] + fa1[I], zgA = ga0[I] + ga1[I];                         \
    float zfB = fb0[I] + fb1[I], zgB = gb0[I] + gb1[I];                         \
    float fgA = __builtin_amdgcn_rcpf(1.f + __builtin_amdgcn_exp2f(zfA));       \
    float thA = 1.f - 2.f * __builtin_amdgcn_rcpf(__builtin_amdgcn_exp2f(zgA) + 1.f); \
    float cnA = fgA * (cregA[I] - thA) + thA;                                   \
    float fgB = __builtin_amdgcn_rcpf(1.f + __builtin_amdgcn_exp2f(zfB));       \
    float thB = 1.f - 2.f * __builtin_amdgcn_rcpf(__builtin_amdgcn_exp2f(zgB) + 1.f); \
    float cnB = fgB * (cregB[I] - thB) + thB;                                   \
    cregA[I] = cnA; cregB[I] = cnB;                                             \
    pkcast pk_; pk_.h = __builtin_amdgcn_cvt_pkrtz(cnA, cnB);                   \
    *(u32t*)(cn_ + woPk[I]) = pk_.u;                                            \
  }

// One recurrence step. Reads c(fp16) from cbuf[P], writes c'(fp16) to cbuf[P^1].
// XC* hold x(TT) raw fp32 (loaded 2 steps ago); refilled with x((TT+2)&255).
#define STEP(XC0, XC1, XC2, XC3, TT, P)                                         \
  {                                                                             \
    const char* cb_ = cbuf[P];                                                  \
    h16x8 ca0 = *(const h16x8*)(cb_ + ro[0]);                                   \
    h16x8 ca1 = *(const h16x8*)(cb_ + ro[1]);                                   \
    h16x8 ca2 = *(const h16x8*)(cb_ + ro[2]);                                   \
    h16x8 ca3 = *(const h16x8*)(cb_ + ro[3]);                                   \
    h8cast ux0, ux1;                                                            \
    ux0.h[0] = __builtin_amdgcn_cvt_pkrtz(XC0[0], XC0[1]);                      \
    ux0.h[1] = __builtin_amdgcn_cvt_pkrtz(XC0[2], XC0[3]);                      \
    ux0.h[2] = __builtin_amdgcn_cvt_pkrtz(XC1[0], XC1[1]);                      \
    ux0.h[3] = __builtin_amdgcn_cvt_pkrtz(XC1[2], XC1[3]);                      \
    ux1.h[0] = __builtin_amdgcn_cvt_pkrtz(XC2[0], XC2[1]);                      \
    ux1.h[1] = __builtin_amdgcn_cvt_pkrtz(XC2[2], XC2[3]);                      \
    ux1.h[2] = __builtin_amdgcn_cvt_pkrtz(XC3[0], XC3[1]);                      \
    ux1.h[3] = __builtin_amdgcn_cvt_pkrtz(XC3[2], XC3[3]);                      \
    const h16x8 xa0 = ux0.v, xa1 = ux1.v;                                       \
    /* refill: uniform byte offset (t+2)&255)*IN, per-lane base */              \
    {                                                                           \
      const int tn = ((TT) + 2) & (T - 1);                                      \
      const float* xp = xbase + (size_t)tn * IN;                                \
      XC0 = *(const f4*)(xp);                                                   \
      XC1 = *(const f4*)(xp + 4);                                               \
      XC2 = *(const f4*)(xp + 32);                                              \
      XC3 = *(const f4*)(xp + 36);                                              \
    }                                                                           \
    /* 8 parallel depth-3 MFMA chains */                                        \
    f32x4 fa0 = __builtin_amdgcn_mfma_f32_16x16x32_f16(xa0, bA0, bqA, 0, 0, 0); \
    f32x4 fb0 = __builtin_amdgcn_mfma_f32_16x16x32_f16(xa0, bB0, bqB, 0, 0, 0); \
    f32x4 ga0 = __builtin_amdgcn_mfma_f32_16x16x32_f16(xa0, bC0, bqC, 0, 0, 0); \
    f32x4 gb0 = __builtin_amdgcn_mfma_f32_16x16x32_f16(xa0, bD0, bqD, 0, 0, 0); \
    f32x4 fa1 = __builtin_amdgcn_mfma_f32_16x16x32_f16(xa1, bA1, zq, 0, 0, 0);  \
    f32x4 fb1 = __builtin_amdgcn_mfma_f32_16x16x32_f16(xa1, bB1, zq, 0, 0, 0);  \
    f32x4 ga1 = __builtin_amdgcn_mfma_f32_16x16x32_f16(xa1, bC1, zq, 0, 0, 0);  \
    f32x4 gb1 = __builtin_amdgcn_mfma_f32_16x16x32_f16(xa1, bD1, zq, 0, 0, 0);  \
    fa0 = __builtin_amdgcn_mfma_f32_16x16x32_f16(ca0, bA2, fa0, 0, 0, 0);       \
    fb0 = __builtin_amdgcn_mfma_f32_16x16x32_f16(ca0, bB2, fb0, 0, 0, 0);       \
    ga0 = __builtin_amdgcn_mfma_f32_16x16x32_f16(ca0, bC2, ga0, 0, 0, 0);       \
    gb0 = __builtin_amdgcn_mfma_f32_16x16x32_f16(ca0, bD2, gb0, 0, 0, 0);       \
    fa1 = __builtin_amdgcn_mfma_f32_16x16x32_f16(ca1, bA3, fa1, 0, 0, 0);       \
    fb1 = __builtin_amdgcn_mfma_f32_16x16x32_f16(ca1, bB3, fb1, 0, 0, 0);       \
    ga1 = __builtin_amdgcn_mfma_f32_16x16x32_f16(ca1, bC3, ga1, 0, 0, 0);       \
    gb1 = __builtin_amdgcn_mfma_f32_16x16x32_f16(ca1, bD3, gb1, 0, 0, 0);       \
    fa0 = __builtin_amdgcn_mfma_f32_16x16x32_f16(ca2, bA4, fa0, 0, 0, 0);       \
    fb0 = __builtin_amdgcn_mfma_f32_16x16x32_f16(ca2, bB4, fb0, 0, 0, 0);       \
    ga0 = __builtin_amdgcn_mfma_f32_16x16x32_f16(ca2, bC4, ga0, 0, 0, 0);       \
    gb0 = __builtin_amdgcn_mfma_f32_16x16x32_f16(ca2, bD4, gb0, 0, 0, 0);       \
    fa1 = __builtin_amdgcn_mfma_f32_16x16x32_f16(ca3, bA5, fa1, 0, 0, 0);       \
    fb1 = __builtin_amdgcn_mfma_f32_16x16x32_f16(ca3, bB5, fb1, 0, 0, 0);       \
    ga1 = __builtin_amdgcn_mfma_f32_16x16x32_f16(ca3, bC5, ga1, 0, 0, 0);       \
    gb1 = __builtin_amdgcn_mfma_f32_16x16x32_f16(ca3, bD5, gb1, 0, 0, 0);       \
    char* cn_ = cbuf[(P) ^ 1];                                                  \
    GATEPK(0) GATEPK(1) GATEPK(2) GATEPK(3)                                     \
    /* LDS-only barrier: ds_writes visible, global prefetch stays in flight */  \
    asm volatile("s_waitcnt lgkmcnt(0)\n\ts_barrier" ::: "memory");             \
  }

__global__ __launch_bounds__(256, 1)
void llrnn_f16(const float* __restrict__ in,   // [B,T,IN]
               const float* __restrict__ Km,   // [IN,ZDIM]
               const float* __restrict__ Rm,   // [CELL,ZDIM]
               const float* __restrict__ bz,   // [ZDIM]
               const float* __restrict__ Wd,   // [CELL,OUTD]
               const float* __restrict__ bd,   // [OUTD]
               float* __restrict__ out)        // [B,OUTD]
{
  // c state as fp16 [16 rows][128 cells], chunk-XOR-swizzled, double-buffered.
  // byte(r,j) = r*256 + 16*((j>>3)^(r&7)) + (2j&15)
  __shared__ __align__(16) char cbuf[2][M * CELL * 2];   // 2 x 4 KB
  __shared__ float cfin[M * CELL];

  const int tid = threadIdx.x;
  const int w = tid >> 6;        // wave 0..3
  const int l = tid & 63;
  const int q = l & 15;          // A-row / D-col within tile
  const int g = l >> 4;          // k-group 0..3
  const int rb = blockIdx.x * M;
  const int colA = 32 * w + 2 * q;    // even cell column owned by this lane
  const int colB = colA + 1;          // odd cell column (adjacent -> packed write)

  // zero c(t=0) buffer (4 KB, 256 threads x 4 u32)
  {
    u32t* z0 = (u32t*)cbuf[0];
    z0[tid] = 0; z0[tid + 256] = 0; z0[tid + 512] = 0; z0[tid + 768] = 0;
  }

  const float SF = -1.44269504f;  // -log2(e): fold into f-gate weights
  const float SG =  2.88539008f;  //  2*log2(e): fold into g-gate weights

  // ---- preload scaled weight columns as fp16 frags (A=f even, B=f odd,
  //      C=g even, D=g odd), pinned in AGPRs (MFMA reads them natively) ----
  h16x8 bA0,bA1,bA2,bA3,bA4,bA5, bB0,bB1,bB2,bB3,bB4,bB5,
        bC0,bC1,bC2,bC3,bC4,bC5, bD0,bD1,bD2,bD3,bD4,bD5;
#define LOADW(DST, COL, KT, SC)                                                 \
  {                                                                             \
    _Pragma("unroll") for (int e = 0; e < 8; ++e) {                             \
      const int krow = 32 * (KT) + 8 * g + e;                                   \
      const float* src = ((KT) < 2) ? (Km + (size_t)krow * ZDIM)                \
                                    : (Rm + (size_t)(krow - IN) * ZDIM);        \
      DST[e] = (_Float16)(src[COL] * (SC));                                     \
    }                                                                           \
  }
  LOADW(bA0,colA,0,SF) LOADW(bA1,colA,1,SF) LOADW(bA2,colA,2,SF)
  LOADW(bA3,colA,3,SF) LOADW(bA4,colA,4,SF) LOADW(bA5,colA,5,SF)
  LOADW(bB0,colB,0,SF) LOADW(bB1,colB,1,SF) LOADW(bB2,colB,2,SF)
  LOADW(bB3,colB,3,SF) LOADW(bB4,colB,4,SF) LOADW(bB5,colB,5,SF)
  LOADW(bC0,colA+CELL,0,SG) LOADW(bC1,colA+CELL,1,SG) LOADW(bC2,colA+CELL,2,SG)
  LOADW(bC3,colA+CELL,3,SG) LOADW(bC4,colA+CELL,4,SG) LOADW(bC5,colA+CELL,5,SG)
  LOADW(bD0,colB+CELL,0,SG) LOADW(bD1,colB+CELL,1,SG) LOADW(bD2,colB+CELL,2,SG)
  LOADW(bD3,colB+CELL,3,SG) LOADW(bD4,colB+CELL,4,SG) LOADW(bD5,colB+CELL,5,SG)
#undef LOADW
  // pin weight frags in AGPRs: frees arch VGPRs, no accvgpr copies for MFMA
  asm volatile("" : "+a"(bA0),"+a"(bA1),"+a"(bA2),"+a"(bA3),"+a"(bA4),"+a"(bA5),
                    "+a"(bB0),"+a"(bB1),"+a"(bB2),"+a"(bB3),"+a"(bB4),"+a"(bB5),
                    "+a"(bC0),"+a"(bC1),"+a"(bC2),"+a"(bC3),"+a"(bC4),"+a"(bC5),
                    "+a"(bD0),"+a"(bD1),"+a"(bD2),"+a"(bD3),"+a"(bD4),"+a"(bD5));

  const float bA_ = bz[colA] * SF, bB_ = bz[colB] * SF;
  const float bC_ = bz[colA + CELL] * SG, bD_ = bz[colB + CELL] * SG;
  f32x4 bqA = {bA_, bA_, bA_, bA_};
  f32x4 bqB = {bB_, bB_, bB_, bB_};
  f32x4 bqC = {bC_, bC_, bC_, bC_};
  f32x4 bqD = {bD_, bD_, bD_, bD_};
  f32x4 zq  = {0.f, 0.f, 0.f, 0.f};
  asm volatile("" : "+v"(bqA), "+v"(bqB), "+v"(bqC), "+v"(bqD), "+v"(zq));

  // LDS byte offsets
  int ro[4];   // read: row q, cells 32ct+8g..+8
#pragma unroll
  for (int ct = 0; ct < 4; ++ct)
    ro[ct] = q * 256 + 16 * ((4 * ct + g) ^ (q & 7));
  int woPk[4]; // packed write: row 4g+i, cells colA,colB (one u32)
#pragma unroll
  for (int i = 0; i < 4; ++i) {
    const int r = 4 * g + i;
    woPk[i] = r * 256 + 16 * ((4 * w + (q >> 2)) ^ (r & 7)) + ((4 * q) & 15);
  }

  // per-lane x base (row rb+q, k-offset 8g); step offset is uniform
  const float* xbase = in + (size_t)(rb + q) * T * IN + 8 * g;
  // prologue: x(0) -> bufA, x(1) -> bufB
  f4 xc0 = *(const f4*)(xbase);
  f4 xc1 = *(const f4*)(xbase + 4);
  f4 xc2 = *(const f4*)(xbase + 32);
  f4 xc3 = *(const f4*)(xbase + 36);
  f4 xn0 = *(const f4*)(xbase + 64);
  f4 xn1 = *(const f4*)(xbase + 68);
  f4 xn2 = *(const f4*)(xbase + 96);
  f4 xn3 = *(const f4*)(xbase + 100);

  f32x4 cregA = {0.f, 0.f, 0.f, 0.f};   // fp32 master state, col colA
  f32x4 cregB = {0.f, 0.f, 0.f, 0.f};   // fp32 master state, col colB

  __syncthreads();   // c(t=0) zeros visible

  for (int t = 0; t < T; t += 2) {
    STEP(xc0, xc1, xc2, xc3, t, 0)       // even: consumes bufA, refills bufA
    STEP(xn0, xn1, xn2, xn3, t + 1, 1)   // odd:  consumes bufB, refills bufB
  }

  // ---- final c (fp32) to LDS, dense epilogue out = h @ Wd + bd ----
#pragma unroll
  for (int i = 0; i < 4; ++i) {
    cfin[(4 * g + i) * CELL + colA] = cregA[i];
    cfin[(4 * g + i) * CELL + colB] = cregB[i];
  }
  __syncthreads();

  const int o = tid & 63;
  const int rp = tid >> 6;   // 0..3: rows rp, rp+4, rp+8, rp+12
  float a0 = bd[o], a1 = bd[o], a2 = bd[o], a3 = bd[o];
#pragma unroll 4
  for (int k = 0; k < CELL; ++k) {
    const float wv = Wd[(size_t)k * OUTD + o];
    a0 += cfin[rp * CELL + k] * wv;
    a1 += cfin[(rp + 4) * CELL + k] * wv;
    a2 += cfin[(rp + 8) * CELL + k] * wv;
    a3 += cfin[(rp + 12) * CELL + k] * wv;
  }
  out[(size_t)(rb + rp) * OUTD + o] = a0;
  out[(size_t)(rb + rp + 4) * OUTD + o] = a1;
  out[(size_t)(rb + rp + 8) * OUTD + o] = a2;
  out[(size_t)(rb + rp + 12) * OUTD + o] = a3;
}

extern "C" void kernel_launch(void* const* d_in, const int* in_sizes, int n_in,
                              void* d_out, int out_size, void* d_ws, size_t ws_size,
                              hipStream_t stream) {
  const float* in  = (const float*)d_in[0];
  const float* Km  = (const float*)d_in[1];
  const float* Rm  = (const float*)d_in[2];
  const float* bz  = (const float*)d_in[3];
  const float* Wd  = (const float*)d_in[4];
  const float* bd  = (const float*)d_in[5];
  float* out = (float*)d_out;

  dim3 grid(BATCH / M);   // 256 blocks -> 1 per CU
  dim3 block(256);        // 4 waves -> 1 per SIMD
  hipLaunchKernelGGL(llrnn_f16, grid, block, 0, stream,
                     in, Km, Rm, bz, Wd, bd, out);
}